// Round 3
// baseline (672.353 us; speedup 1.0000x reference)
//
#include <hip/hip_runtime.h>
#include <hip/hip_bf16.h>

__device__ __forceinline__ float b2f(__hip_bfloat16 v) { return __bfloat162float(v); }

// Branched float load: isF32 ? fp32 : bf16 (flag is grid-uniform)
__device__ __forceinline__ float loadF(const void* p, long long i, int isF32) {
    if (isF32) return ((const float*)p)[i];
    return b2f(((const __hip_bfloat16*)p)[i]);
}

// Branched edge fetch: i64 => [2,E] int64 read as int32 pairs (LE: low word first)
__device__ __forceinline__ void get_edge(const int* ei, int i64, int e, int E, int& s, int& d) {
    if (i64) { s = ei[2 * (long long)e]; d = ei[2 * (long long)E + 2 * (long long)e]; }
    else     { s = ei[e];                d = ei[(long long)E + e]; }
}

// ---- dtype detection: flags[0]=1 if floats are fp32; flags[1]=1 if indices are int64 ----
__global__ void k_detect(const void* x, const int* ei, int* flags) {
    __shared__ int s_sane, s_zero;
    int tid = threadIdx.x;
    if (tid == 0) { s_sane = 0; s_zero = 0; }
    __syncthreads();
    const unsigned short* xu = (const unsigned short*)x;
    int sane = 0;
    for (int k = tid; k < 4096; k += 256) {
        unsigned int bits = ((unsigned int)xu[2 * k]) << 16;  // even bf16 slot
        float v = __uint_as_float(bits);
        float a = fabsf(v);
        if (v == 0.0f || (a >= 9.3e-10f && a <= 1.1e9f)) sane++;
    }
    atomicAdd(&s_sane, sane);
    int zero = 0;
    for (int k = tid; k < 1024; k += 256) {
        if (ei[2 * k + 1] == 0) zero++;  // odd int32 word: int64 high half would be 0
    }
    atomicAdd(&s_zero, zero);
    __syncthreads();
    if (tid == 0) {
        flags[0] = (s_sane < 3000) ? 1 : 0;  // bf16 memory => ~4096 sane; fp32 => ~1000
        flags[1] = (s_zero > 512) ? 1 : 0;
    }
}

// ---- convert weights to fp32: W1f[4096] b1f[64] W2f[1024] b2f[16] ----
__global__ void k_prep(const void* W1, const void* b1, const void* W2, const void* b2,
                       const int* flags, float* Wbuf) {
    int f = flags[0];
    int tid = threadIdx.x;
    for (int i = tid; i < 4096; i += 256) Wbuf[i] = loadF(W1, i, f);
    if (tid < 64) Wbuf[4096 + tid] = loadF(b1, tid, f);
    for (int i = tid; i < 1024; i += 256) Wbuf[4160 + i] = loadF(W2, i, f);
    if (tid < 16) Wbuf[5184 + tid] = loadF(b2, tid, f);
}

// ---- histogram: degf[src]+=1 (for dis), cntd[dst]+=1 (for CSR offsets) ----
__global__ void k_hist(const int* __restrict__ ei, const int* __restrict__ flags, int E,
                       float* __restrict__ degf, int* __restrict__ cntd) {
    int e = blockIdx.x * blockDim.x + threadIdx.x;
    if (e < E) {
        int s, d;
        get_edge(ei, flags[1], e, E, s, d);
        atomicAdd(&degf[s], 1.0f);
        atomicAdd(&cntd[d], 1);
    }
}

// ---- dis[i] = rsqrt(deg[i] + 1)  (self loop) ----
__global__ void k_dis(float* __restrict__ deg, int N) {
    int i = blockIdx.x * blockDim.x + threadIdx.x;
    if (i < N) deg[i] = rsqrtf(deg[i] + 1.0f);
}

// ---- 3-kernel exclusive scan of cntd -> row_start (+cursor copy), chunk=1024/block ----
__global__ void k_scanA(const int* __restrict__ cnt, int N, int* __restrict__ blockSum) {
    __shared__ int part[256];
    int b = blockIdx.x, t = threadIdx.x;
    int base = b * 1024 + t * 4;
    int s = 0;
#pragma unroll
    for (int i = 0; i < 4; ++i) { int idx = base + i; if (idx < N) s += cnt[idx]; }
    part[t] = s;
    __syncthreads();
    for (int off = 128; off; off >>= 1) {
        if (t < off) part[t] += part[t + off];
        __syncthreads();
    }
    if (t == 0) blockSum[b] = part[0];
}

__global__ void k_scanB(int* __restrict__ blockSum, int nb, int* __restrict__ row_start,
                        int N, int E) {
    if (threadIdx.x == 0) {
        int run = 0;
        for (int i = 0; i < nb; ++i) { int v = blockSum[i]; blockSum[i] = run; run += v; }
        row_start[N] = E;
    }
}

__global__ void k_scanC(const int* __restrict__ cnt, int N, const int* __restrict__ blockOff,
                        int* __restrict__ row_start, int* __restrict__ cursor) {
    __shared__ int part[256];
    int b = blockIdx.x, t = threadIdx.x;
    int base = b * 1024 + t * 4;
    int v[4]; int s = 0;
#pragma unroll
    for (int i = 0; i < 4; ++i) { int idx = base + i; v[i] = (idx < N) ? cnt[idx] : 0; s += v[i]; }
    part[t] = s;
    __syncthreads();
    for (int off = 1; off < 256; off <<= 1) {  // Hillis-Steele inclusive
        int add = (t >= off) ? part[t - off] : 0;
        __syncthreads();
        part[t] += add;
        __syncthreads();
    }
    int excl = part[t] - s + blockOff[b];
#pragma unroll
    for (int i = 0; i < 4; ++i) {
        int idx = base + i;
        if (idx < N) { row_start[idx] = excl; cursor[idx] = excl; excl += v[i]; }
    }
}

// ---- fill CSR: csr_src[pos] = src, bucketed by dst ----
__global__ void k_fill(const int* __restrict__ ei, const int* __restrict__ flags, int E,
                       int* __restrict__ cursor, int* __restrict__ csr_src) {
    int e = blockIdx.x * blockDim.x + threadIdx.x;
    if (e < E) {
        int s, d;
        get_edge(ei, flags[1], e, E, s, d);
        int pos = atomicAdd(&cursor[d], 1);
        csr_src[pos] = s;
    }
}

// ---- layer 1 fused: gather-aggregate (no atomics) + relu(acc@W1+b1)@W2 in registers ----
// one wave per node (lane = feature); persistent grid-stride; W1 col + W2 slice in VGPRs
__global__ __launch_bounds__(256) void k_l1(const void* __restrict__ x,
                                            const int* __restrict__ flags,
                                            const float* __restrict__ dis,
                                            const int* __restrict__ row_start,
                                            const int* __restrict__ csr_src,
                                            const float* __restrict__ Wbuf,
                                            float* __restrict__ T2, int N) {
    int f = flags[0];
    int lane = threadIdx.x & 63;
    int wave = (blockIdx.x * blockDim.x + threadIdx.x) >> 6;
    int nwaves = (gridDim.x * blockDim.x) >> 6;
    int j2 = lane & 15, kk = lane >> 4;
    float w1c[64];
#pragma unroll
    for (int k = 0; k < 64; ++k) w1c[k] = Wbuf[k * 64 + lane];        // W1[:,lane]
    float w2c[16];
#pragma unroll
    for (int k0 = 0; k0 < 16; ++k0) w2c[k0] = Wbuf[4160 + (kk * 16 + k0) * 16 + j2];
    float b1v = Wbuf[4096 + lane];

    for (int n = wave; n < N; n += nwaves) {
        float dd = dis[n];
        float acc = dd * dd * loadF(x, (long long)n * 64 + lane, f);  // self loop
        int beg = row_start[n], end = row_start[n + 1];
        for (int base = beg; base < end; base += 64) {
            int m = min(64, end - base);
            int idx = (lane < m) ? csr_src[base + lane] : 0;          // coalesced index load
            float dsv = (lane < m) ? dis[idx] : 0.0f;
            for (int k = 0; k < m; ++k) {
                int s = __shfl(idx, k);
                float nrm = dd * __shfl(dsv, k);
                acc += nrm * loadF(x, (long long)s * 64 + lane, f);   // coalesced row gather
            }
        }
        // h[lane] = relu(b1 + sum_k acc_k * W1[k][lane])  -- acc_k via shuffle
        float h = b1v;
#pragma unroll
        for (int k = 0; k < 64; ++k) h += __shfl(acc, k) * w1c[k];
        h = fmaxf(h, 0.0f);
        // T2[n][j2] = sum_k h_k * W2[k][j2], split-K over 4 lane-groups
        float a2 = 0.0f;
#pragma unroll
        for (int k0 = 0; k0 < 16; ++k0) a2 += __shfl(h, kk * 16 + k0) * w2c[k0];
        a2 += __shfl_down(a2, 16);
        a2 += __shfl_down(a2, 32);
        if (lane < 16) T2[(long long)n * 16 + lane] = a2;
    }
}

// ---- layer 2 fused: gather-aggregate T2 (16 lanes/node) + b2 + log_softmax -> out ----
__global__ __launch_bounds__(256) void k_l2(const float* __restrict__ T2,
                                            const int* __restrict__ flags,
                                            const float* __restrict__ dis,
                                            const int* __restrict__ row_start,
                                            const int* __restrict__ csr_src,
                                            const float* __restrict__ Wbuf,
                                            void* __restrict__ out, int N) {
    int isF32 = flags[0];
    int t = blockIdx.x * blockDim.x + threadIdx.x;
    int g = t >> 4;
    int l = t & 15;
    int ngroups = (gridDim.x * blockDim.x) >> 4;
    float b2v = Wbuf[5184 + l];
    for (int n = g; n < N; n += ngroups) {
        float dd = dis[n];
        float acc = dd * dd * T2[(long long)n * 16 + l];
        int beg = row_start[n], end = row_start[n + 1];
        for (int base = beg; base < end; base += 16) {
            int m = min(16, end - base);
            int idx = (l < m) ? csr_src[base + l] : 0;
            float dsv = (l < m) ? dis[idx] : 0.0f;
            for (int k = 0; k < m; ++k) {
                int s = __shfl(idx, k, 16);
                float nrm = dd * __shfl(dsv, k, 16);
                acc += nrm * T2[(long long)s * 16 + l];
            }
        }
        float v = acc + b2v;
        float mx = v;
#pragma unroll
        for (int off = 8; off; off >>= 1) mx = fmaxf(mx, __shfl_xor(mx, off, 16));
        float ex = __expf(v - mx);
        float ss = ex;
#pragma unroll
        for (int off = 8; off; off >>= 1) ss += __shfl_xor(ss, off, 16);
        float r = v - mx - logf(ss);
        long long oi = (long long)n * 16 + l;
        if (isF32) ((float*)out)[oi] = r;
        else       ((__hip_bfloat16*)out)[oi] = __float2bfloat16(r);
    }
}

extern "C" void kernel_launch(void* const* d_in, const int* in_sizes, int n_in,
                              void* d_out, int out_size, void* d_ws, size_t ws_size,
                              hipStream_t stream) {
    const void* x  = d_in[0];
    const int*  ei = (const int*)d_in[1];
    const void* W1 = d_in[2];
    const void* b1 = d_in[3];
    const void* W2 = d_in[4];
    const void* b2 = d_in[5];

    const int N = in_sizes[0] / 64;   // 100000
    const int E = in_sizes[1] / 2;    // 1200000
    const int nb = (N + 1023) / 1024; // scan blocks

    // ws layout: flags[2] | dis[N] | cntd[N] | row_start[N+1] | cursor[N] | blockSum[nb]
    //            | csr_src[E] | T2[16N] | Wbuf[5200]   (~13 MB total)
    char* p = (char*)d_ws;
    int*   flags     = (int*)p;                 p += 16;
    float* dis       = (float*)p;               p += (size_t)N * 4;
    int*   cntd      = (int*)p;                 p += (size_t)N * 4;
    int*   row_start = (int*)p;                 p += (size_t)(N + 4) * 4;
    int*   cursor    = (int*)p;                 p += (size_t)N * 4;
    int*   blockSum  = (int*)p;                 p += (size_t)((nb + 3) & ~3) * 4;
    int*   csr_src   = (int*)p;                 p += (size_t)E * 4;
    float* T2        = (float*)p;               p += (size_t)N * 16 * 4;
    float* Wbuf      = (float*)p;

    k_detect<<<1, 256, 0, stream>>>(x, ei, flags);
    hipMemsetAsync(dis,  0, (size_t)N * 4, stream);
    hipMemsetAsync(cntd, 0, (size_t)N * 4, stream);
    k_hist<<<(E + 255) / 256, 256, 0, stream>>>(ei, flags, E, dis, cntd);
    k_dis<<<(N + 255) / 256, 256, 0, stream>>>(dis, N);
    k_scanA<<<nb, 256, 0, stream>>>(cntd, N, blockSum);
    k_scanB<<<1, 64, 0, stream>>>(blockSum, nb, row_start, N, E);
    k_scanC<<<nb, 256, 0, stream>>>(cntd, N, blockSum, row_start, cursor);
    k_fill<<<(E + 255) / 256, 256, 0, stream>>>(ei, flags, E, cursor, csr_src);
    k_prep<<<1, 256, 0, stream>>>(W1, b1, W2, b2, flags, Wbuf);
    k_l1<<<1024, 256, 0, stream>>>(x, flags, dis, row_start, csr_src, Wbuf, T2, N);
    k_l2<<<512, 256, 0, stream>>>(T2, flags, dis, row_start, csr_src, Wbuf, d_out, N);
}

// Round 4
// 501.484 us; speedup vs baseline: 1.3407x; 1.3407x over previous
//
#include <hip/hip_runtime.h>
#include <hip/hip_bf16.h>

__device__ __forceinline__ float b2f(__hip_bfloat16 v) { return __bfloat162float(v); }

// Branched float load: isF32 ? fp32 : bf16 (flag is grid-uniform)
__device__ __forceinline__ float loadF(const void* p, long long i, int isF32) {
    if (isF32) return ((const float*)p)[i];
    return b2f(((const __hip_bfloat16*)p)[i]);
}

// vector load of 4 consecutive features: element row base + 4*i4
__device__ __forceinline__ float4 loadF4(const void* p, long long base, int i4, int isF32) {
    if (isF32) {
        return ((const float4*)((const float*)p + base))[i4];
    } else {
        ushort4 u = ((const ushort4*)((const unsigned short*)p + base))[i4];
        float4 r;
        r.x = __uint_as_float(((unsigned)u.x) << 16);
        r.y = __uint_as_float(((unsigned)u.y) << 16);
        r.z = __uint_as_float(((unsigned)u.z) << 16);
        r.w = __uint_as_float(((unsigned)u.w) << 16);
        return r;
    }
}

// Branched edge fetch: i64 => [2,E] int64 read as int32 pairs (LE: low word first)
__device__ __forceinline__ void get_edge(const int* ei, int i64, int e, int E, int& s, int& d) {
    if (i64) { s = ei[2 * (long long)e]; d = ei[2 * (long long)E + 2 * (long long)e]; }
    else     { s = ei[e];                d = ei[(long long)E + e]; }
}

// ---- dtype detection: flags[0]=1 if floats are fp32; flags[1]=1 if indices are int64 ----
__global__ void k_detect(const void* x, const int* ei, int* flags) {
    __shared__ int s_sane, s_zero;
    int tid = threadIdx.x;
    if (tid == 0) { s_sane = 0; s_zero = 0; }
    __syncthreads();
    const unsigned short* xu = (const unsigned short*)x;
    int sane = 0;
    for (int k = tid; k < 4096; k += 256) {
        unsigned int bits = ((unsigned int)xu[2 * k]) << 16;  // even bf16 slot
        float v = __uint_as_float(bits);
        float a = fabsf(v);
        if (v == 0.0f || (a >= 9.3e-10f && a <= 1.1e9f)) sane++;
    }
    atomicAdd(&s_sane, sane);
    int zero = 0;
    for (int k = tid; k < 1024; k += 256) {
        if (ei[2 * k + 1] == 0) zero++;
    }
    atomicAdd(&s_zero, zero);
    __syncthreads();
    if (tid == 0) {
        flags[0] = (s_sane < 3000) ? 1 : 0;
        flags[1] = (s_zero > 512) ? 1 : 0;
    }
}

// ---- convert weights to fp32: W1f[4096] b1f[64] W2f[1024] b2f[16] ----
__global__ void k_prep(const void* W1, const void* b1, const void* W2, const void* b2,
                       const int* flags, float* Wbuf) {
    int f = flags[0];
    int tid = threadIdx.x;
    for (int i = tid; i < 4096; i += 256) Wbuf[i] = loadF(W1, i, f);
    if (tid < 64) Wbuf[4096 + tid] = loadF(b1, tid, f);
    for (int i = tid; i < 1024; i += 256) Wbuf[4160 + i] = loadF(W2, i, f);
    if (tid < 16) Wbuf[5184 + tid] = loadF(b2, tid, f);
}

// ---- histogram: degf[src]+=1 (for dis), cntd[dst]+=1 (for CSR offsets) ----
__global__ void k_hist(const int* __restrict__ ei, const int* __restrict__ flags, int E,
                       float* __restrict__ degf, int* __restrict__ cntd) {
    int e = blockIdx.x * blockDim.x + threadIdx.x;
    if (e < E) {
        int s, d;
        get_edge(ei, flags[1], e, E, s, d);
        atomicAdd(&degf[s], 1.0f);
        atomicAdd(&cntd[d], 1);
    }
}

// ---- dis[i] = rsqrt(deg[i] + 1)  (self loop) ----
__global__ void k_dis(float* __restrict__ deg, int N) {
    int i = blockIdx.x * blockDim.x + threadIdx.x;
    if (i < N) deg[i] = rsqrtf(deg[i] + 1.0f);
}

// ---- 3-kernel exclusive scan of cntd -> row_start (+cursor copy) ----
__global__ void k_scanA(const int* __restrict__ cnt, int N, int* __restrict__ blockSum) {
    __shared__ int part[256];
    int b = blockIdx.x, t = threadIdx.x;
    int base = b * 1024 + t * 4;
    int s = 0;
#pragma unroll
    for (int i = 0; i < 4; ++i) { int idx = base + i; if (idx < N) s += cnt[idx]; }
    part[t] = s;
    __syncthreads();
    for (int off = 128; off; off >>= 1) {
        if (t < off) part[t] += part[t + off];
        __syncthreads();
    }
    if (t == 0) blockSum[b] = part[0];
}

__global__ void k_scanB(int* __restrict__ blockSum, int nb, int* __restrict__ row_start,
                        int N, int E) {
    if (threadIdx.x == 0) {
        int run = 0;
        for (int i = 0; i < nb; ++i) { int v = blockSum[i]; blockSum[i] = run; run += v; }
        row_start[N] = E;
    }
}

__global__ void k_scanC(const int* __restrict__ cnt, int N, const int* __restrict__ blockOff,
                        int* __restrict__ row_start, int* __restrict__ cursor) {
    __shared__ int part[256];
    int b = blockIdx.x, t = threadIdx.x;
    int base = b * 1024 + t * 4;
    int v[4]; int s = 0;
#pragma unroll
    for (int i = 0; i < 4; ++i) { int idx = base + i; v[i] = (idx < N) ? cnt[idx] : 0; s += v[i]; }
    part[t] = s;
    __syncthreads();
    for (int off = 1; off < 256; off <<= 1) {
        int add = (t >= off) ? part[t - off] : 0;
        __syncthreads();
        part[t] += add;
        __syncthreads();
    }
    int excl = part[t] - s + blockOff[b];
#pragma unroll
    for (int i = 0; i < 4; ++i) {
        int idx = base + i;
        if (idx < N) { row_start[idx] = excl; cursor[idx] = excl; excl += v[i]; }
    }
}

// ---- fill CSR: csr_src[pos] = src, bucketed by dst ----
__global__ void k_fill(const int* __restrict__ ei, const int* __restrict__ flags, int E,
                       int* __restrict__ cursor, int* __restrict__ csr_src) {
    int e = blockIdx.x * blockDim.x + threadIdx.x;
    if (e < E) {
        int s, d;
        get_edge(ei, flags[1], e, E, s, d);
        int pos = atomicAdd(&cursor[d], 1);
        csr_src[pos] = s;
    }
}

// ---- layer 1 fused: wave/node, 4 edge-slots x 16 feature-lanes (float4), then
//      relu(agg@W1+b1)@W2 in-wave (W1/W2 in LDS) ----
__global__ __launch_bounds__(256) void k_l1(const void* __restrict__ x,
                                            const int* __restrict__ flags,
                                            const float* __restrict__ dis,
                                            const int* __restrict__ row_start,
                                            const int* __restrict__ csr_src,
                                            const float* __restrict__ Wbuf,
                                            float* __restrict__ T2, int N) {
    __shared__ float W1s[4096];
    __shared__ float W2s[1024];
    int tid = threadIdx.x;
    for (int i = tid; i < 4096; i += 256) W1s[i] = Wbuf[i];
    for (int i = tid; i < 1024; i += 256) W2s[i] = Wbuf[4160 + i];
    __syncthreads();

    int f = flags[0];
    int lane = tid & 63;
    int g = lane >> 4;    // edge slot
    int i4 = lane & 15;   // feature quad
    float b1v = Wbuf[4096 + lane];

    int n = blockIdx.x * 4 + (tid >> 6);
    if (n >= N) return;

    float dd = dis[n];
    float4 acc = make_float4(0.f, 0.f, 0.f, 0.f);
    if (g == 0) {  // self loop
        float4 xv = loadF4(x, (long long)n * 64, i4, f);
        float w = dd * dd;
        acc.x = w * xv.x; acc.y = w * xv.y; acc.z = w * xv.z; acc.w = w * xv.w;
    }
    int beg = row_start[n], end = row_start[n + 1];
    for (int base = beg; base < end; base += 64) {
        int m = min(64, end - base);
        int idxv = (lane < m) ? csr_src[base + lane] : 0;   // coalesced
        float dsv = (lane < m) ? dis[idxv] : 0.0f;
        int nb = (m + 3) >> 2;
        int t = 0;
        for (; t + 2 <= nb; t += 2) {  // 2x unroll: 8 loads in flight per wave
            int q0 = 4 * t + g, q1 = q0 + 4;
            int s0 = __shfl(idxv, q0), s1 = __shfl(idxv, q1);
            float nr0 = dd * __shfl(dsv, q0), nr1 = dd * __shfl(dsv, q1);
            float4 x0 = loadF4(x, (long long)s0 * 64, i4, f);
            float4 x1 = loadF4(x, (long long)s1 * 64, i4, f);
            acc.x += nr0 * x0.x; acc.y += nr0 * x0.y; acc.z += nr0 * x0.z; acc.w += nr0 * x0.w;
            acc.x += nr1 * x1.x; acc.y += nr1 * x1.y; acc.z += nr1 * x1.z; acc.w += nr1 * x1.w;
        }
        if (t < nb) {
            int q0 = 4 * t + g;
            int s0 = __shfl(idxv, q0);
            float nr0 = dd * __shfl(dsv, q0);
            float4 x0 = loadF4(x, (long long)s0 * 64, i4, f);
            acc.x += nr0 * x0.x; acc.y += nr0 * x0.y; acc.z += nr0 * x0.z; acc.w += nr0 * x0.w;
        }
    }
    // cross-slot reduce: all lanes hold agg[4*i4 .. 4*i4+3]
    acc.x += __shfl_xor(acc.x, 16); acc.y += __shfl_xor(acc.y, 16);
    acc.z += __shfl_xor(acc.z, 16); acc.w += __shfl_xor(acc.w, 16);
    acc.x += __shfl_xor(acc.x, 32); acc.y += __shfl_xor(acc.y, 32);
    acc.z += __shfl_xor(acc.z, 32); acc.w += __shfl_xor(acc.w, 32);

    // h[lane] = relu(b1 + sum_k agg[k] * W1[k][lane])
    float h = b1v;
#pragma unroll
    for (int kq = 0; kq < 16; ++kq) {
        float ax = __shfl(acc.x, kq);
        float ay = __shfl(acc.y, kq);
        float az = __shfl(acc.z, kq);
        float aw = __shfl(acc.w, kq);
        h += ax * W1s[(4 * kq + 0) * 64 + lane];
        h += ay * W1s[(4 * kq + 1) * 64 + lane];
        h += az * W1s[(4 * kq + 2) * 64 + lane];
        h += aw * W1s[(4 * kq + 3) * 64 + lane];
    }
    h = fmaxf(h, 0.0f);

    // T2[n][i4] = sum_k h_k * W2[k][i4], split-K over the 4 slots
    float a2 = 0.0f;
#pragma unroll
    for (int kk = 0; kk < 16; ++kk) {
        float hk = __shfl(h, 16 * g + kk);
        a2 += hk * W2s[(16 * g + kk) * 16 + i4];
    }
    a2 += __shfl_xor(a2, 16);
    a2 += __shfl_xor(a2, 32);
    if (g == 0) T2[(long long)n * 16 + i4] = a2;
}

// ---- layer 2 fused: wave/node, 4 edge-slots x 16 features + b2 + log_softmax ----
__global__ __launch_bounds__(256) void k_l2(const float* __restrict__ T2,
                                            const int* __restrict__ flags,
                                            const float* __restrict__ dis,
                                            const int* __restrict__ row_start,
                                            const int* __restrict__ csr_src,
                                            const float* __restrict__ Wbuf,
                                            void* __restrict__ out, int N) {
    int isF32 = flags[0];
    int tid = threadIdx.x;
    int lane = tid & 63;
    int g = lane >> 4, i = lane & 15;
    float b2v = Wbuf[5184 + i];

    int n = blockIdx.x * 4 + (tid >> 6);
    if (n >= N) return;

    float dd = dis[n];
    float acc = (g == 0) ? dd * dd * T2[(long long)n * 16 + i] : 0.0f;
    int beg = row_start[n], end = row_start[n + 1];
    for (int base = beg; base < end; base += 64) {
        int m = min(64, end - base);
        int idxv = (lane < m) ? csr_src[base + lane] : 0;
        float dsv = (lane < m) ? dis[idxv] : 0.0f;
        int nb = (m + 3) >> 2;
        int t = 0;
        for (; t + 2 <= nb; t += 2) {
            int q0 = 4 * t + g, q1 = q0 + 4;
            int s0 = __shfl(idxv, q0), s1 = __shfl(idxv, q1);
            float nr0 = dd * __shfl(dsv, q0), nr1 = dd * __shfl(dsv, q1);
            float v0 = T2[(long long)s0 * 16 + i];
            float v1 = T2[(long long)s1 * 16 + i];
            acc += nr0 * v0;
            acc += nr1 * v1;
        }
        if (t < nb) {
            int q0 = 4 * t + g;
            int s0 = __shfl(idxv, q0);
            float nr0 = dd * __shfl(dsv, q0);
            acc += nr0 * T2[(long long)s0 * 16 + i];
        }
    }
    acc += __shfl_xor(acc, 16);
    acc += __shfl_xor(acc, 32);
    float v = acc + b2v;
    float mx = v;
#pragma unroll
    for (int off = 8; off; off >>= 1) mx = fmaxf(mx, __shfl_xor(mx, off, 16));
    float ex = __expf(v - mx);
    float ss = ex;
#pragma unroll
    for (int off = 8; off; off >>= 1) ss += __shfl_xor(ss, off, 16);
    float r = v - mx - logf(ss);
    if (g == 0) {
        long long oi = (long long)n * 16 + i;
        if (isF32) ((float*)out)[oi] = r;
        else       ((__hip_bfloat16*)out)[oi] = __float2bfloat16(r);
    }
}

extern "C" void kernel_launch(void* const* d_in, const int* in_sizes, int n_in,
                              void* d_out, int out_size, void* d_ws, size_t ws_size,
                              hipStream_t stream) {
    const void* x  = d_in[0];
    const int*  ei = (const int*)d_in[1];
    const void* W1 = d_in[2];
    const void* b1 = d_in[3];
    const void* W2 = d_in[4];
    const void* b2 = d_in[5];

    const int N = in_sizes[0] / 64;   // 100000
    const int E = in_sizes[1] / 2;    // 1200000
    const int nb = (N + 1023) / 1024;

    // ws: flags[2] | dis[N] | cntd[N] | row_start[N+1] | cursor[N] | blockSum | csr_src[E]
    //     | T2[16N] | Wbuf[5200]   (~13 MB)
    char* p = (char*)d_ws;
    int*   flags     = (int*)p;                 p += 16;
    float* dis       = (float*)p;               p += (size_t)N * 4;
    int*   cntd      = (int*)p;                 p += (size_t)N * 4;
    int*   row_start = (int*)p;                 p += (size_t)(N + 4) * 4;
    int*   cursor    = (int*)p;                 p += (size_t)N * 4;
    int*   blockSum  = (int*)p;                 p += (size_t)((nb + 3) & ~3) * 4;
    int*   csr_src   = (int*)p;                 p += (size_t)E * 4;
    float* T2        = (float*)p;               p += (size_t)N * 16 * 4;
    float* Wbuf      = (float*)p;

    k_detect<<<1, 256, 0, stream>>>(x, ei, flags);
    hipMemsetAsync(dis,  0, (size_t)N * 4, stream);
    hipMemsetAsync(cntd, 0, (size_t)N * 4, stream);
    k_hist<<<(E + 255) / 256, 256, 0, stream>>>(ei, flags, E, dis, cntd);
    k_dis<<<(N + 255) / 256, 256, 0, stream>>>(dis, N);
    k_scanA<<<nb, 256, 0, stream>>>(cntd, N, blockSum);
    k_scanB<<<1, 64, 0, stream>>>(blockSum, nb, row_start, N, E);
    k_scanC<<<nb, 256, 0, stream>>>(cntd, N, blockSum, row_start, cursor);
    k_fill<<<(E + 255) / 256, 256, 0, stream>>>(ei, flags, E, cursor, csr_src);
    k_prep<<<1, 256, 0, stream>>>(W1, b1, W2, b2, flags, Wbuf);
    k_l1<<<(N + 3) / 4, 256, 0, stream>>>(x, flags, dis, row_start, csr_src, Wbuf, T2, N);
    k_l2<<<(N + 3) / 4, 256, 0, stream>>>(T2, flags, dis, row_start, csr_src, Wbuf, d_out, N);
}

// Round 5
// 378.098 us; speedup vs baseline: 1.7782x; 1.3263x over previous
//
#include <hip/hip_runtime.h>
#include <hip/hip_bf16.h>

typedef __attribute__((ext_vector_type(8))) short bfrag;
typedef __attribute__((ext_vector_type(4))) float ffrag;

__device__ __forceinline__ float b2f_(unsigned short u) {
    return __uint_as_float(((unsigned)u) << 16);
}
__device__ __forceinline__ unsigned short f2b_(float v) {
    __hip_bfloat16 h = __float2bfloat16(v);   // RNE
    return *reinterpret_cast<unsigned short*>(&h);
}

// Branched float load: isF32 ? fp32 : bf16 (flag is grid-uniform)
__device__ __forceinline__ float loadF(const void* p, long long i, int isF32) {
    if (isF32) return ((const float*)p)[i];
    return b2f_(((const unsigned short*)p)[i]);
}

// vector load of 4 consecutive features at element (base + 4*i4)
__device__ __forceinline__ float4 loadF4(const void* p, long long base, int i4, int isF32) {
    if (isF32) {
        return ((const float4*)((const float*)p + base))[i4];
    } else {
        ushort4 u = ((const ushort4*)((const unsigned short*)p + base))[i4];
        return make_float4(b2f_(u.x), b2f_(u.y), b2f_(u.z), b2f_(u.w));
    }
}

// Branched edge fetch: i64 => int64 read as int32 pairs (LE: low word first)
__device__ __forceinline__ void get_edge(const int* ei, int i64, int e, int E, int& s, int& d) {
    if (i64) { s = ei[2 * (long long)e]; d = ei[2 * (long long)E + 2 * (long long)e]; }
    else     { s = ei[e];                d = ei[(long long)E + e]; }
}

// masked packed-CSR fetch: entry = {src, dis[src]}; nrm masked to 0 past end
__device__ __forceinline__ int2 fetchE(const int2* pke, int p, int end) {
    int pc = max(min(p, end - 1), 0);
    int2 v = pke[pc];
    v.y = (p < end) ? v.y : 0;
    return v;
}

// ---- dtype detection + weight conversion (one block) ----
__global__ void k_detect_prep(const void* x, const int* ei,
                              const void* W1, const void* b1, const void* W2, const void* b2,
                              int* flags, float* Wbuf) {
    __shared__ int s_sane, s_zero, s_f;
    int tid = threadIdx.x;
    if (tid == 0) { s_sane = 0; s_zero = 0; }
    __syncthreads();
    const unsigned short* xu = (const unsigned short*)x;
    int sane = 0;
    for (int k = tid; k < 4096; k += 256) {
        float v = b2f_(xu[2 * k]);     // even bf16 slot
        float a = fabsf(v);
        if (v == 0.0f || (a >= 9.3e-10f && a <= 1.1e9f)) sane++;
    }
    atomicAdd(&s_sane, sane);
    int zero = 0;
    for (int k = tid; k < 1024; k += 256) if (ei[2 * k + 1] == 0) zero++;
    atomicAdd(&s_zero, zero);
    __syncthreads();
    if (tid == 0) {
        int f = (s_sane < 3000) ? 1 : 0;
        flags[0] = f;
        flags[1] = (s_zero > 512) ? 1 : 0;
        s_f = f;
    }
    __syncthreads();
    int f = s_f;
    for (int i = tid; i < 4096; i += 256) Wbuf[i] = loadF(W1, i, f);
    if (tid < 64) Wbuf[4096 + tid] = loadF(b1, tid, f);
    for (int i = tid; i < 1024; i += 256) Wbuf[4160 + i] = loadF(W2, i, f);
    if (tid < 16) Wbuf[5184 + tid] = loadF(b2, tid, f);
}

// ---- histogram: degf[src]+=1 (becomes dis), cntd[dst]+=1 (CSR offsets) ----
__global__ void k_hist(const int* __restrict__ ei, const int* __restrict__ flags, int E,
                       float* __restrict__ degf, int* __restrict__ cntd) {
    int e = blockIdx.x * blockDim.x + threadIdx.x;
    if (e < E) {
        int s, d;
        get_edge(ei, flags[1], e, E, s, d);
        atomicAdd(&degf[s], 1.0f);
        atomicAdd(&cntd[d], 1);
    }
}

// ---- scanA (block sums of cntd) fused with dis[i] = rsqrt(deg+1) ----
__global__ void k_scanA_dis(const int* __restrict__ cnt, int N, int* __restrict__ blockSum,
                            float* __restrict__ dis) {
    __shared__ int part[256];
    int b = blockIdx.x, t = threadIdx.x;
    int base = b * 1024 + t * 4;
    int s = 0;
#pragma unroll
    for (int i = 0; i < 4; ++i) {
        int idx = base + i;
        if (idx < N) { s += cnt[idx]; dis[idx] = rsqrtf(dis[idx] + 1.0f); }
    }
    part[t] = s;
    __syncthreads();
    for (int off = 128; off; off >>= 1) {
        if (t < off) part[t] += part[t + off];
        __syncthreads();
    }
    if (t == 0) blockSum[b] = part[0];
}

__global__ void k_scanB(int* __restrict__ blockSum, int nb, int* __restrict__ row_start,
                        int N, int E) {
    if (threadIdx.x == 0) {
        int run = 0;
        for (int i = 0; i < nb; ++i) { int v = blockSum[i]; blockSum[i] = run; run += v; }
        row_start[N] = E;
    }
}

__global__ void k_scanC(const int* __restrict__ cnt, int N, const int* __restrict__ blockOff,
                        int* __restrict__ row_start, int* __restrict__ cursor) {
    __shared__ int part[256];
    int b = blockIdx.x, t = threadIdx.x;
    int base = b * 1024 + t * 4;
    int v[4]; int s = 0;
#pragma unroll
    for (int i = 0; i < 4; ++i) { int idx = base + i; v[i] = (idx < N) ? cnt[idx] : 0; s += v[i]; }
    part[t] = s;
    __syncthreads();
    for (int off = 1; off < 256; off <<= 1) {
        int add = (t >= off) ? part[t - off] : 0;
        __syncthreads();
        part[t] += add;
        __syncthreads();
    }
    int excl = part[t] - s + blockOff[b];
#pragma unroll
    for (int i = 0; i < 4; ++i) {
        int idx = base + i;
        if (idx < N) { row_start[idx] = excl; cursor[idx] = excl; excl += v[i]; }
    }
}

// ---- fill packed CSR: pke[pos] = {src, dis[src]} bucketed by dst ----
__global__ void k_fill(const int* __restrict__ ei, const int* __restrict__ flags, int E,
                       const float* __restrict__ dis,
                       int* __restrict__ cursor, int2* __restrict__ pke) {
    int e = blockIdx.x * blockDim.x + threadIdx.x;
    if (e < E) {
        int s, d;
        get_edge(ei, flags[1], e, E, s, d);
        int pos = atomicAdd(&cursor[d], 1);
        pke[pos] = make_int2(s, __float_as_int(dis[s]));
    }
}

// ---- aggregation only: AGG[n] = dd^2*x[n] + sum dd*dis[s]*x[s]  -> bf16 [N,64] ----
// wave per node: 4 edge-slots x 16 feature-lanes, 2-deep pipelined (4 loads in flight)
__global__ __launch_bounds__(256) void k_agg(const void* __restrict__ x,
                                             const int* __restrict__ flags,
                                             const float* __restrict__ dis,
                                             const int* __restrict__ row_start,
                                             const int2* __restrict__ pke,
                                             unsigned short* __restrict__ aggb, int N) {
    int f = flags[0];
    int tid = threadIdx.x;
    int lane = tid & 63;
    int g = lane >> 4, i4 = lane & 15;
    int n = blockIdx.x * 4 + (tid >> 6);
    if (n >= N) return;
    float dd = dis[n];
    int beg = row_start[n], end = row_start[n + 1];
    int cnt = end - beg;
    float4 a0 = make_float4(0.f, 0.f, 0.f, 0.f), a1 = make_float4(0.f, 0.f, 0.f, 0.f);
    if (g == 0) {  // self loop
        float4 xv = loadF4(x, (long long)n * 64, i4, f);
        float w = dd * dd;
        a0.x = w * xv.x; a0.y = w * xv.y; a0.z = w * xv.z; a0.w = w * xv.w;
    }
    int nIt = (cnt + 3) >> 2;
    int p = beg + g;
    int2 e0 = fetchE(pke, p, end);
    int2 e1 = fetchE(pke, p + 4, end);
    int t = 0;
    for (; t + 2 <= nIt; t += 2) {
        float4 r0 = loadF4(x, (long long)e0.x * 64, i4, f);
        float4 r1 = loadF4(x, (long long)e1.x * 64, i4, f);
        float n0v = dd * __int_as_float(e0.y);
        float n1v = dd * __int_as_float(e1.y);
        e0 = fetchE(pke, p + 8, end);
        e1 = fetchE(pke, p + 12, end);
        p += 8;
        a0.x += n0v * r0.x; a0.y += n0v * r0.y; a0.z += n0v * r0.z; a0.w += n0v * r0.w;
        a1.x += n1v * r1.x; a1.y += n1v * r1.y; a1.z += n1v * r1.z; a1.w += n1v * r1.w;
    }
    if (t < nIt) {
        float4 r0 = loadF4(x, (long long)e0.x * 64, i4, f);
        float n0v = dd * __int_as_float(e0.y);
        a0.x += n0v * r0.x; a0.y += n0v * r0.y; a0.z += n0v * r0.z; a0.w += n0v * r0.w;
    }
    a0.x += a1.x; a0.y += a1.y; a0.z += a1.z; a0.w += a1.w;
    a0.x += __shfl_xor(a0.x, 16); a0.y += __shfl_xor(a0.y, 16);
    a0.z += __shfl_xor(a0.z, 16); a0.w += __shfl_xor(a0.w, 16);
    a0.x += __shfl_xor(a0.x, 32); a0.y += __shfl_xor(a0.y, 32);
    a0.z += __shfl_xor(a0.z, 32); a0.w += __shfl_xor(a0.w, 32);
    if (g == 0) {
        ushort4 o;
        o.x = f2b_(a0.x); o.y = f2b_(a0.y); o.z = f2b_(a0.z); o.w = f2b_(a0.w);
        *(ushort4*)(aggb + (size_t)n * 64 + i4 * 4) = o;
    }
}

// ---- dense chain via MFMA: T2 = relu(AGG@W1 + b1) @ W2  (bf16 in/out) ----
// wave = 16-node tile (N % 16 == 0 for N=100000); block = 4 waves = 64 nodes.
// A-frag: lane(m=lane&15, q=lane>>4) holds A[m][q*8+j]; B-frag: B[q*8+j][lane&15];
// D-frag: row=q*4+reg, col=lane&15 (verified layouts, learn_hip m89/m91).
__global__ __launch_bounds__(256) void k_dense(const unsigned short* __restrict__ aggb,
                                               const float* __restrict__ Wbuf,
                                               unsigned short* __restrict__ t2b, int N) {
    __shared__ unsigned short Hs[4][16 * 72];   // per-wave H tile, stride 72 (16B-aligned rows)
    int tid = threadIdx.x;
    int lane = tid & 63;
    int w = tid >> 6;
    int m = lane & 15, q = lane >> 4;
    int n0 = blockIdx.x * 64 + w * 16;
    if (n0 >= N) return;   // no cross-wave LDS sharing; no barrier needed

    // B fragments (bf16) for W1 [64x64] and W2 [64x16], built from fp32 Wbuf
    bfrag Bw1[2][4];
#pragma unroll
    for (int kt = 0; kt < 2; ++kt)
#pragma unroll
        for (int nt = 0; nt < 4; ++nt)
#pragma unroll
            for (int j = 0; j < 8; ++j)
                Bw1[kt][nt][j] = (short)f2b_(Wbuf[(kt * 32 + q * 8 + j) * 64 + nt * 16 + m]);
    bfrag Bw2[2];
#pragma unroll
    for (int kt = 0; kt < 2; ++kt)
#pragma unroll
        for (int j = 0; j < 8; ++j)
            Bw2[kt][j] = (short)f2b_(Wbuf[4160 + (kt * 32 + q * 8 + j) * 16 + m]);
    float b1n[4];
#pragma unroll
    for (int nt = 0; nt < 4; ++nt) b1n[nt] = Wbuf[4096 + nt * 16 + m];

    // A fragments from AGG (16B per lane, aligned)
    const unsigned short* arow = aggb + (size_t)(n0 + m) * 64 + q * 8;
    bfrag A0 = *(const bfrag*)(arow);
    bfrag A1 = *(const bfrag*)(arow + 32);

    ffrag acc[4];
#pragma unroll
    for (int nt = 0; nt < 4; ++nt) {
        ffrag z = {0.f, 0.f, 0.f, 0.f};
        z = __builtin_amdgcn_mfma_f32_16x16x32_bf16(A0, Bw1[0][nt], z, 0, 0, 0);
        z = __builtin_amdgcn_mfma_f32_16x16x32_bf16(A1, Bw1[1][nt], z, 0, 0, 0);
        acc[nt] = z;
    }
    // H = relu(acc + b1) -> LDS (D-layout -> row-major), then reload as A-frags
    unsigned short* hs = &Hs[w][0];
#pragma unroll
    for (int nt = 0; nt < 4; ++nt)
#pragma unroll
        for (int r = 0; r < 4; ++r) {
            float hv = fmaxf(acc[nt][r] + b1n[nt], 0.0f);
            hs[(q * 4 + r) * 72 + nt * 16 + m] = f2b_(hv);
        }
    const unsigned short* hrow = hs + m * 72 + q * 8;
    bfrag H0 = *(const bfrag*)(hrow);
    bfrag H1 = *(const bfrag*)(hrow + 32);
    ffrag t2 = {0.f, 0.f, 0.f, 0.f};
    t2 = __builtin_amdgcn_mfma_f32_16x16x32_bf16(H0, Bw2[0], t2, 0, 0, 0);
    t2 = __builtin_amdgcn_mfma_f32_16x16x32_bf16(H1, Bw2[1], t2, 0, 0, 0);
#pragma unroll
    for (int r = 0; r < 4; ++r)
        t2b[(size_t)(n0 + q * 4 + r) * 16 + m] = f2b_(t2[r]);
}

// ---- layer 2: gather T2 (bf16, 32B rows) + b2 + log_softmax -> out ----
__global__ __launch_bounds__(256) void k_l2(const unsigned short* __restrict__ t2b,
                                            const int* __restrict__ flags,
                                            const float* __restrict__ dis,
                                            const int* __restrict__ row_start,
                                            const int2* __restrict__ pke,
                                            const float* __restrict__ Wbuf,
                                            void* __restrict__ out, int N) {
    int isF32 = flags[0];
    int tid = threadIdx.x, lane = tid & 63;
    int g = lane >> 4, i = lane & 15;
    int n = blockIdx.x * 4 + (tid >> 6);
    if (n >= N) return;
    float dd = dis[n];
    int beg = row_start[n], end = row_start[n + 1];
    int cnt = end - beg;
    float a0 = 0.f, a1 = 0.f;
    if (g == 0) a0 = dd * dd * b2f_(t2b[(size_t)n * 16 + i]);
    int nIt = (cnt + 3) >> 2;
    int p = beg + g;
    int2 e0 = fetchE(pke, p, end);
    int2 e1 = fetchE(pke, p + 4, end);
    int t = 0;
    for (; t + 2 <= nIt; t += 2) {
        float r0 = b2f_(t2b[(size_t)e0.x * 16 + i]);
        float r1 = b2f_(t2b[(size_t)e1.x * 16 + i]);
        float n0v = dd * __int_as_float(e0.y);
        float n1v = dd * __int_as_float(e1.y);
        e0 = fetchE(pke, p + 8, end);
        e1 = fetchE(pke, p + 12, end);
        p += 8;
        a0 += n0v * r0;
        a1 += n1v * r1;
    }
    if (t < nIt) {
        float r0 = b2f_(t2b[(size_t)e0.x * 16 + i]);
        a0 += dd * __int_as_float(e0.y) * r0;
    }
    a0 += a1;
    a0 += __shfl_xor(a0, 16);
    a0 += __shfl_xor(a0, 32);
    float v = a0 + Wbuf[5184 + i];
    float mx = v;
#pragma unroll
    for (int off = 8; off; off >>= 1) mx = fmaxf(mx, __shfl_xor(mx, off, 16));
    float ex = __expf(v - mx);
    float ss = ex;
#pragma unroll
    for (int off = 8; off; off >>= 1) ss += __shfl_xor(ss, off, 16);
    float r = v - mx - logf(ss);
    if (g == 0) {
        size_t oi = (size_t)n * 16 + i;
        if (isF32) ((float*)out)[oi] = r;
        else       ((unsigned short*)out)[oi] = f2b_(r);
    }
}

extern "C" void kernel_launch(void* const* d_in, const int* in_sizes, int n_in,
                              void* d_out, int out_size, void* d_ws, size_t ws_size,
                              hipStream_t stream) {
    const void* x  = d_in[0];
    const int*  ei = (const int*)d_in[1];
    const void* W1 = d_in[2];
    const void* b1 = d_in[3];
    const void* W2 = d_in[4];
    const void* b2 = d_in[5];

    const int N = in_sizes[0] / 64;   // 100000
    const int E = in_sizes[1] / 2;    // 1200000
    const int nb = (N + 1023) / 1024;

    // ws: flags | dis[N] | cntd[N] | row_start[N+1] | cursor[N] | blockSum | pke[2E]
    //     | aggb[64N u16] | t2b[16N u16] | Wbuf[5200 f32]   (~27 MB)
    char* p = (char*)d_ws;
    int*   flags     = (int*)p;                   p += 16;
    float* dis       = (float*)p;                 p += (size_t)N * 4;
    int*   cntd      = (int*)p;                   p += (size_t)N * 4;
    int*   row_start = (int*)p;                   p += (size_t)(N + 4) * 4;
    int*   cursor    = (int*)p;                   p += (size_t)N * 4;
    int*   blockSum  = (int*)p;                   p += (size_t)((nb + 3) & ~3) * 4;
    int2*  pke       = (int2*)p;                  p += (size_t)E * 8;
    unsigned short* aggb = (unsigned short*)p;    p += (size_t)N * 64 * 2;
    unsigned short* t2b  = (unsigned short*)p;    p += (size_t)N * 16 * 2;
    float* Wbuf      = (float*)p;

    hipMemsetAsync(dis,  0, (size_t)N * 4, stream);
    hipMemsetAsync(cntd, 0, (size_t)N * 4, stream);
    k_detect_prep<<<1, 256, 0, stream>>>(x, ei, W1, b1, W2, b2, flags, Wbuf);
    k_hist<<<(E + 255) / 256, 256, 0, stream>>>(ei, flags, E, dis, cntd);
    k_scanA_dis<<<nb, 256, 0, stream>>>(cntd, N, blockSum, dis);
    k_scanB<<<1, 64, 0, stream>>>(blockSum, nb, row_start, N, E);
    k_scanC<<<nb, 256, 0, stream>>>(cntd, N, blockSum, row_start, cursor);
    k_fill<<<(E + 255) / 256, 256, 0, stream>>>(ei, flags, E, dis, cursor, pke);
    k_agg<<<(N + 3) / 4, 256, 0, stream>>>(x, flags, dis, row_start, pke, aggb, N);
    k_dense<<<(N + 63) / 64, 256, 0, stream>>>(aggb, Wbuf, t2b, N);
    k_l2<<<(N + 3) / 4, 256, 0, stream>>>(t2b, flags, dis, row_start, pke, Wbuf, d_out, N);
}

// Round 6
// 273.512 us; speedup vs baseline: 2.4582x; 1.3824x over previous
//
#include <hip/hip_runtime.h>
#include <hip/hip_bf16.h>

typedef __attribute__((ext_vector_type(8))) short bfrag;
typedef __attribute__((ext_vector_type(4))) float ffrag;

// bucket = 256 consecutive nodes; supports N <= 131072 (static LDS hist arrays)
#define BSH 8
#define LBS 256

__device__ __forceinline__ float b2f_(unsigned short u) {
    return __uint_as_float(((unsigned)u) << 16);
}
__device__ __forceinline__ unsigned short f2b_(float v) {
    __hip_bfloat16 h = __float2bfloat16(v);   // RNE
    return *reinterpret_cast<unsigned short*>(&h);
}

__device__ __forceinline__ float loadF(const void* p, long long i, int isF32) {
    if (isF32) return ((const float*)p)[i];
    return b2f_(((const unsigned short*)p)[i]);
}

__device__ __forceinline__ float4 loadF4(const void* p, long long base, int i4, int isF32) {
    if (isF32) {
        return ((const float4*)((const float*)p + base))[i4];
    } else {
        ushort4 u = ((const ushort4*)((const unsigned short*)p + base))[i4];
        return make_float4(b2f_(u.x), b2f_(u.y), b2f_(u.z), b2f_(u.w));
    }
}

__device__ __forceinline__ void get_edge(const int* ei, int i64, int e, int E, int& s, int& d) {
    if (i64) { s = ei[2 * (long long)e]; d = ei[2 * (long long)E + 2 * (long long)e]; }
    else     { s = ei[e];                d = ei[(long long)E + e]; }
}

__device__ __forceinline__ int2 fetchE(const int2* pke, int p, int end) {
    int pc = max(min(p, end - 1), 0);
    int2 v = pke[pc];
    v.y = (p < end) ? v.y : 0;
    return v;
}

// ---- dtype detection + weight conversion (one block) ----
__global__ void k_detect_prep(const void* x, const int* ei,
                              const void* W1, const void* b1, const void* W2, const void* b2,
                              int* flags, float* Wbuf) {
    __shared__ int s_sane, s_zero, s_f;
    int tid = threadIdx.x;
    if (tid == 0) { s_sane = 0; s_zero = 0; }
    __syncthreads();
    const unsigned short* xu = (const unsigned short*)x;
    int sane = 0;
    for (int k = tid; k < 4096; k += 256) {
        float v = b2f_(xu[2 * k]);
        float a = fabsf(v);
        if (v == 0.0f || (a >= 9.3e-10f && a <= 1.1e9f)) sane++;
    }
    atomicAdd(&s_sane, sane);
    int zero = 0;
    for (int k = tid; k < 1024; k += 256) if (ei[2 * k + 1] == 0) zero++;
    atomicAdd(&s_zero, zero);
    __syncthreads();
    if (tid == 0) {
        int f = (s_sane < 3000) ? 1 : 0;
        flags[0] = f;
        flags[1] = (s_zero > 512) ? 1 : 0;
        s_f = f;
    }
    __syncthreads();
    int f = s_f;
    for (int i = tid; i < 4096; i += 256) Wbuf[i] = loadF(W1, i, f);
    if (tid < 64) Wbuf[4096 + tid] = loadF(b1, tid, f);
    for (int i = tid; i < 1024; i += 256) Wbuf[4160 + i] = loadF(W2, i, f);
    if (tid < 16) Wbuf[5184 + tid] = loadF(b2, tid, f);
}

// ---- C1: coarse bucket counts via LDS hist; ~nbk global atomics per block ----
__global__ __launch_bounds__(256) void k_count(const int* __restrict__ ei,
                                               const int* __restrict__ flags, int E, int nbk,
                                               int* __restrict__ dcnt_g, int* __restrict__ scnt_g) {
    __shared__ int h[1024];   // [0..512): dst-bucket, [512..1024): src-bucket
    int tid = threadIdx.x;
    for (int i = tid; i < 1024; i += 256) h[i] = 0;
    __syncthreads();
    int i64 = flags[1];
    int stride = blockDim.x * gridDim.x;
    for (int e = blockIdx.x * blockDim.x + tid; e < E; e += stride) {
        int s, d;
        get_edge(ei, i64, e, E, s, d);
        atomicAdd(&h[d >> BSH], 1);
        atomicAdd(&h[512 + (s >> BSH)], 1);
    }
    __syncthreads();
    for (int i = tid; i < nbk; i += 256) {
        if (h[i])       atomicAdd(&dcnt_g[i], h[i]);
        if (h[512 + i]) atomicAdd(&scnt_g[i], h[512 + i]);
    }
}

// ---- C2: scan both bucket-count arrays -> bases + cursors; row_start[N]=E ----
__global__ void k_scan2(const int* __restrict__ dcnt, const int* __restrict__ scnt,
                        int nbk, int E, int N,
                        int* __restrict__ dbase, int* __restrict__ dcur,
                        int* __restrict__ sbase, int* __restrict__ scur,
                        int* __restrict__ row_start) {
    __shared__ int ld[512], ls[512];
    int tid = threadIdx.x;
    for (int i = tid; i < nbk; i += 256) { ld[i] = dcnt[i]; ls[i] = scnt[i]; }
    __syncthreads();
    if (tid == 0) { int run = 0; for (int i = 0; i < nbk; ++i) { int v = ld[i]; ld[i] = run; run += v; } }
    if (tid == 1) { int run = 0; for (int i = 0; i < nbk; ++i) { int v = ls[i]; ls[i] = run; run += v; } }
    __syncthreads();
    for (int i = tid; i < nbk; i += 256) {
        dbase[i] = ld[i]; dcur[i] = ld[i];
        sbase[i] = ls[i]; scur[i] = ls[i];
    }
    if (tid == 0) { dbase[nbk] = E; sbase[nbk] = E; row_start[N] = E; }
}

// ---- C3: bucket-fill via per-block LDS count + chunk claim + plain stores ----
// dst-stream: packed (src<<8)|(dst&255) int; src-stream: (src&255) byte
__global__ __launch_bounds__(256) void k_bfill(const int* __restrict__ ei,
                                               const int* __restrict__ flags, int E, int nbk,
                                               int* __restrict__ dcur_g, int* __restrict__ scur_g,
                                               int* __restrict__ pdst,
                                               unsigned char* __restrict__ psrc) {
    __shared__ int hd[512], hs[512], bd[512], bs[512];
    int tid = threadIdx.x;
    for (int i = tid; i < 512; i += 256) { hd[i] = 0; hs[i] = 0; }
    __syncthreads();
    int i64 = flags[1];
    int stride = blockDim.x * gridDim.x;
    for (int e = blockIdx.x * blockDim.x + tid; e < E; e += stride) {
        int s, d;
        get_edge(ei, i64, e, E, s, d);
        atomicAdd(&hd[d >> BSH], 1);
        atomicAdd(&hs[s >> BSH], 1);
    }
    __syncthreads();
    for (int i = tid; i < nbk; i += 256) {
        int v = hd[i];
        bd[i] = v ? atomicAdd(&dcur_g[i], v) : 0;
        v = hs[i];
        bs[i] = v ? atomicAdd(&scur_g[i], v) : 0;
    }
    __syncthreads();
    for (int e = blockIdx.x * blockDim.x + tid; e < E; e += stride) {
        int s, d;
        get_edge(ei, i64, e, E, s, d);
        int p = atomicAdd(&bd[d >> BSH], 1);
        pdst[p] = (s << BSH) | (d & (LBS - 1));
        int q = atomicAdd(&bs[s >> BSH], 1);
        psrc[q] = (unsigned char)(s & (LBS - 1));
    }
}

// ---- C4: exact per-node src degree per bucket -> dis = rsqrt(deg+1) ----
__global__ __launch_bounds__(256) void k_deg(const unsigned char* __restrict__ psrc,
                                             const int* __restrict__ sbase,
                                             float* __restrict__ dis, int N) {
    __shared__ int h[LBS];
    int b = blockIdx.x, tid = threadIdx.x;
    if (tid < LBS) h[tid] = 0;
    __syncthreads();
    int beg = sbase[b], end = sbase[b + 1];
    for (int p = beg + tid; p < end; p += 256) atomicAdd(&h[psrc[p]], 1);
    __syncthreads();
    if (tid < LBS) {
        int node = b * LBS + tid;
        if (node < N) dis[node] = rsqrtf((float)h[tid] + 1.0f);
    }
}

// ---- C5: exact per-node CSR within bucket: row_start + pke{src, dis[src]} ----
__global__ __launch_bounds__(256) void k_csr(const int* __restrict__ pdst,
                                             const int* __restrict__ dbase,
                                             const float* __restrict__ dis,
                                             int* __restrict__ row_start,
                                             int2* __restrict__ pke, int N) {
    __shared__ int h[LBS], lb[LBS], cur[LBS];
    int b = blockIdx.x, tid = threadIdx.x;
    if (tid < LBS) h[tid] = 0;
    __syncthreads();
    int beg = dbase[b], end = dbase[b + 1];
    for (int p = beg + tid; p < end; p += 256) atomicAdd(&h[pdst[p] & (LBS - 1)], 1);
    __syncthreads();
    if (tid == 0) { int run = 0; for (int i = 0; i < LBS; ++i) { lb[i] = run; run += h[i]; } }
    __syncthreads();
    if (tid < LBS) {
        cur[tid] = lb[tid];
        int node = b * LBS + tid;
        if (node < N) row_start[node] = beg + lb[tid];
    }
    __syncthreads();
    for (int p = beg + tid; p < end; p += 256) {
        int e = pdst[p];
        int src = e >> BSH, ld = e & (LBS - 1);
        int r = atomicAdd(&cur[ld], 1);
        pke[beg + r] = make_int2(src, __float_as_int(dis[src]));
    }
}

// ---- aggregation: AGG[n] = dd^2*x[n] + sum dd*dis[s]*x[s]  -> bf16 [N,64] ----
__global__ __launch_bounds__(256) void k_agg(const void* __restrict__ x,
                                             const int* __restrict__ flags,
                                             const float* __restrict__ dis,
                                             const int* __restrict__ row_start,
                                             const int2* __restrict__ pke,
                                             unsigned short* __restrict__ aggb, int N) {
    int f = flags[0];
    int tid = threadIdx.x;
    int lane = tid & 63;
    int g = lane >> 4, i4 = lane & 15;
    int n = blockIdx.x * 4 + (tid >> 6);
    if (n >= N) return;
    float dd = dis[n];
    int beg = row_start[n], end = row_start[n + 1];
    int cnt = end - beg;
    float4 a0 = make_float4(0.f, 0.f, 0.f, 0.f), a1 = make_float4(0.f, 0.f, 0.f, 0.f);
    if (g == 0) {
        float4 xv = loadF4(x, (long long)n * 64, i4, f);
        float w = dd * dd;
        a0.x = w * xv.x; a0.y = w * xv.y; a0.z = w * xv.z; a0.w = w * xv.w;
    }
    int nIt = (cnt + 3) >> 2;
    int p = beg + g;
    int2 e0 = fetchE(pke, p, end);
    int2 e1 = fetchE(pke, p + 4, end);
    int t = 0;
    for (; t + 2 <= nIt; t += 2) {
        float4 r0 = loadF4(x, (long long)e0.x * 64, i4, f);
        float4 r1 = loadF4(x, (long long)e1.x * 64, i4, f);
        float n0v = dd * __int_as_float(e0.y);
        float n1v = dd * __int_as_float(e1.y);
        e0 = fetchE(pke, p + 8, end);
        e1 = fetchE(pke, p + 12, end);
        p += 8;
        a0.x += n0v * r0.x; a0.y += n0v * r0.y; a0.z += n0v * r0.z; a0.w += n0v * r0.w;
        a1.x += n1v * r1.x; a1.y += n1v * r1.y; a1.z += n1v * r1.z; a1.w += n1v * r1.w;
    }
    if (t < nIt) {
        float4 r0 = loadF4(x, (long long)e0.x * 64, i4, f);
        float n0v = dd * __int_as_float(e0.y);
        a0.x += n0v * r0.x; a0.y += n0v * r0.y; a0.z += n0v * r0.z; a0.w += n0v * r0.w;
    }
    a0.x += a1.x; a0.y += a1.y; a0.z += a1.z; a0.w += a1.w;
    a0.x += __shfl_xor(a0.x, 16); a0.y += __shfl_xor(a0.y, 16);
    a0.z += __shfl_xor(a0.z, 16); a0.w += __shfl_xor(a0.w, 16);
    a0.x += __shfl_xor(a0.x, 32); a0.y += __shfl_xor(a0.y, 32);
    a0.z += __shfl_xor(a0.z, 32); a0.w += __shfl_xor(a0.w, 32);
    if (g == 0) {
        ushort4 o;
        o.x = f2b_(a0.x); o.y = f2b_(a0.y); o.z = f2b_(a0.z); o.w = f2b_(a0.w);
        *(ushort4*)(aggb + (size_t)n * 64 + i4 * 4) = o;
    }
}

// ---- dense chain via MFMA: T2 = relu(AGG@W1 + b1) @ W2  (bf16 in/out) ----
__global__ __launch_bounds__(256) void k_dense(const unsigned short* __restrict__ aggb,
                                               const float* __restrict__ Wbuf,
                                               unsigned short* __restrict__ t2b, int N) {
    __shared__ unsigned short Hs[4][16 * 72];
    int tid = threadIdx.x;
    int lane = tid & 63;
    int w = tid >> 6;
    int m = lane & 15, q = lane >> 4;
    int n0 = blockIdx.x * 64 + w * 16;
    if (n0 >= N) return;

    bfrag Bw1[2][4];
#pragma unroll
    for (int kt = 0; kt < 2; ++kt)
#pragma unroll
        for (int nt = 0; nt < 4; ++nt)
#pragma unroll
            for (int j = 0; j < 8; ++j)
                Bw1[kt][nt][j] = (short)f2b_(Wbuf[(kt * 32 + q * 8 + j) * 64 + nt * 16 + m]);
    bfrag Bw2[2];
#pragma unroll
    for (int kt = 0; kt < 2; ++kt)
#pragma unroll
        for (int j = 0; j < 8; ++j)
            Bw2[kt][j] = (short)f2b_(Wbuf[4160 + (kt * 32 + q * 8 + j) * 16 + m]);
    float b1n[4];
#pragma unroll
    for (int nt = 0; nt < 4; ++nt) b1n[nt] = Wbuf[4096 + nt * 16 + m];

    const unsigned short* arow = aggb + (size_t)(n0 + m) * 64 + q * 8;
    bfrag A0 = *(const bfrag*)(arow);
    bfrag A1 = *(const bfrag*)(arow + 32);

    ffrag acc[4];
#pragma unroll
    for (int nt = 0; nt < 4; ++nt) {
        ffrag z = {0.f, 0.f, 0.f, 0.f};
        z = __builtin_amdgcn_mfma_f32_16x16x32_bf16(A0, Bw1[0][nt], z, 0, 0, 0);
        z = __builtin_amdgcn_mfma_f32_16x16x32_bf16(A1, Bw1[1][nt], z, 0, 0, 0);
        acc[nt] = z;
    }
    unsigned short* hs = &Hs[w][0];
#pragma unroll
    for (int nt = 0; nt < 4; ++nt)
#pragma unroll
        for (int r = 0; r < 4; ++r) {
            float hv = fmaxf(acc[nt][r] + b1n[nt], 0.0f);
            hs[(q * 4 + r) * 72 + nt * 16 + m] = f2b_(hv);
        }
    const unsigned short* hrow = hs + m * 72 + q * 8;
    bfrag H0 = *(const bfrag*)(hrow);
    bfrag H1 = *(const bfrag*)(hrow + 32);
    ffrag t2 = {0.f, 0.f, 0.f, 0.f};
    t2 = __builtin_amdgcn_mfma_f32_16x16x32_bf16(H0, Bw2[0], t2, 0, 0, 0);
    t2 = __builtin_amdgcn_mfma_f32_16x16x32_bf16(H1, Bw2[1], t2, 0, 0, 0);
#pragma unroll
    for (int r = 0; r < 4; ++r)
        t2b[(size_t)(n0 + q * 4 + r) * 16 + m] = f2b_(t2[r]);
}

// ---- layer 2: gather T2 (bf16) + b2 + log_softmax -> out ----
__global__ __launch_bounds__(256) void k_l2(const unsigned short* __restrict__ t2b,
                                            const int* __restrict__ flags,
                                            const float* __restrict__ dis,
                                            const int* __restrict__ row_start,
                                            const int2* __restrict__ pke,
                                            const float* __restrict__ Wbuf,
                                            void* __restrict__ out, int N) {
    int isF32 = flags[0];
    int tid = threadIdx.x, lane = tid & 63;
    int g = lane >> 4, i = lane & 15;
    int n = blockIdx.x * 4 + (tid >> 6);
    if (n >= N) return;
    float dd = dis[n];
    int beg = row_start[n], end = row_start[n + 1];
    int cnt = end - beg;
    float a0 = 0.f, a1 = 0.f;
    if (g == 0) a0 = dd * dd * b2f_(t2b[(size_t)n * 16 + i]);
    int nIt = (cnt + 3) >> 2;
    int p = beg + g;
    int2 e0 = fetchE(pke, p, end);
    int2 e1 = fetchE(pke, p + 4, end);
    int t = 0;
    for (; t + 2 <= nIt; t += 2) {
        float r0 = b2f_(t2b[(size_t)e0.x * 16 + i]);
        float r1 = b2f_(t2b[(size_t)e1.x * 16 + i]);
        float n0v = dd * __int_as_float(e0.y);
        float n1v = dd * __int_as_float(e1.y);
        e0 = fetchE(pke, p + 8, end);
        e1 = fetchE(pke, p + 12, end);
        p += 8;
        a0 += n0v * r0;
        a1 += n1v * r1;
    }
    if (t < nIt) {
        float r0 = b2f_(t2b[(size_t)e0.x * 16 + i]);
        a0 += dd * __int_as_float(e0.y) * r0;
    }
    a0 += a1;
    a0 += __shfl_xor(a0, 16);
    a0 += __shfl_xor(a0, 32);
    float v = a0 + Wbuf[5184 + i];
    float mx = v;
#pragma unroll
    for (int off = 8; off; off >>= 1) mx = fmaxf(mx, __shfl_xor(mx, off, 16));
    float ex = __expf(v - mx);
    float ss = ex;
#pragma unroll
    for (int off = 8; off; off >>= 1) ss += __shfl_xor(ss, off, 16);
    float r = v - mx - logf(ss);
    if (g == 0) {
        size_t oi = (size_t)n * 16 + i;
        if (isF32) ((float*)out)[oi] = r;
        else       ((unsigned short*)out)[oi] = f2b_(r);
    }
}

extern "C" void kernel_launch(void* const* d_in, const int* in_sizes, int n_in,
                              void* d_out, int out_size, void* d_ws, size_t ws_size,
                              hipStream_t stream) {
    const void* x  = d_in[0];
    const int*  ei = (const int*)d_in[1];
    const void* W1 = d_in[2];
    const void* b1 = d_in[3];
    const void* W2 = d_in[4];
    const void* b2 = d_in[5];

    const int N = in_sizes[0] / 64;     // 100000
    const int E = in_sizes[1] / 2;      // 1200000
    const int nbk = (N + LBS - 1) >> BSH;  // 391 coarse buckets

    // ws: flags | Wbuf | dis[N] | row_start[N+1] | dcnt/scnt[nbk] | dbase/sbase[nbk+1]
    //     | dcur/scur[nbk] | pdst[E int] | psrc[E byte] | pke[E int2] | aggb | t2b  (~33 MB)
    char* p = (char*)d_ws;
    int*   flags     = (int*)p;                   p += 16;
    float* Wbuf      = (float*)p;                 p += 5200 * 4;
    float* dis       = (float*)p;                 p += (size_t)N * 4;
    int*   row_start = (int*)p;                   p += (size_t)(N + 4) * 4;
    int*   dcnt_g    = (int*)p;                   p += (size_t)nbk * 4;
    int*   scnt_g    = (int*)p;                   p += (size_t)nbk * 4;   // contiguous w/ dcnt
    int*   dbase_g   = (int*)p;                   p += (size_t)(nbk + 4) * 4;
    int*   sbase_g   = (int*)p;                   p += (size_t)(nbk + 4) * 4;
    int*   dcur_g    = (int*)p;                   p += (size_t)nbk * 4;
    int*   scur_g    = (int*)p;                   p += (size_t)nbk * 4;
    int*   pdst      = (int*)p;                   p += (size_t)E * 4;
    unsigned char* psrc = (unsigned char*)p;      p += ((size_t)E + 15) & ~15ull;
    int2*  pke       = (int2*)p;                  p += (size_t)E * 8;
    unsigned short* aggb = (unsigned short*)p;    p += (size_t)N * 64 * 2;
    unsigned short* t2b  = (unsigned short*)p;

    k_detect_prep<<<1, 256, 0, stream>>>(x, ei, W1, b1, W2, b2, flags, Wbuf);
    hipMemsetAsync(dcnt_g, 0, (size_t)nbk * 2 * 4, stream);
    k_count<<<128, 256, 0, stream>>>(ei, flags, E, nbk, dcnt_g, scnt_g);
    k_scan2<<<1, 256, 0, stream>>>(dcnt_g, scnt_g, nbk, E, N,
                                   dbase_g, dcur_g, sbase_g, scur_g, row_start);
    k_bfill<<<128, 256, 0, stream>>>(ei, flags, E, nbk, dcur_g, scur_g, pdst, psrc);
    k_deg<<<nbk, 256, 0, stream>>>(psrc, sbase_g, dis, N);
    k_csr<<<nbk, 256, 0, stream>>>(pdst, dbase_g, dis, row_start, pke, N);
    k_agg<<<(N + 3) / 4, 256, 0, stream>>>(x, flags, dis, row_start, pke, aggb, N);
    k_dense<<<(N + 63) / 64, 256, 0, stream>>>(aggb, Wbuf, t2b, N);
    k_l2<<<(N + 3) / 4, 256, 0, stream>>>(t2b, flags, dis, row_start, pke, Wbuf, d_out, N);
}